// Round 12
// baseline (232.903 us; speedup 1.0000x reference)
//
#include <hip/hip_runtime.h>

#define DIN 128
#define HID 128
#define DOUT 64
#define NCHUNK 784   // edge chunks (hist/scatter blocks); CH = ceil(E/784) must be <= 2048
#define CHB 8        // edges per thread in bscatter (CHB*256 >= CH)
#define BSH 9        // bucket covers 512 nodes; nb1 = ceil(N/512) must be <= 256
#define NB1MAX 256
#define BSLACK 1540  // per-bucket pad slack (multiple of 4, >= 3*512+4)
#define EBMAX 16384  // bfinal LDS staging entries (seg ~8.2K + pad ~1.5K << 16K)

typedef unsigned short ushort_t;
typedef unsigned int uint_t;
typedef __attribute__((ext_vector_type(4))) short s4v;
typedef __attribute__((ext_vector_type(4))) float f4v;

#if defined(__has_builtin)
#if __has_builtin(__builtin_amdgcn_mfma_f32_16x16x16bf16_1k)
#define MFMA16(a, b, c) __builtin_amdgcn_mfma_f32_16x16x16bf16_1k(a, b, c, 0, 0, 0)
#endif
#endif
#ifndef MFMA16
static __device__ inline f4v mfma16_asm(s4v a, s4v b, f4v c) {
  asm volatile("v_mfma_f32_16x16x16_bf16 %0, %1, %2, %0" : "+v"(c) : "v"(a), "v"(b));
  return c;
}
#define MFMA16(a, b, c) mfma16_asm(a, b, c)
#endif

static inline int ceil_div(int a, int b) { return (a + b - 1) / b; }

__device__ inline ushort_t f2bf(float f) {  // round-to-nearest-even
  uint_t u = __float_as_uint(f);
  u += 0x7fff + ((u >> 16) & 1);
  return (ushort_t)(u >> 16);
}
__device__ inline uint_t pack2bf(float a, float b) {
  return (uint_t)f2bf(a) | ((uint_t)f2bf(b) << 16);
}
__device__ inline float2 bf2x2(uint_t u) {  // unpack 2 bf16 -> 2 f32 (exact)
  return make_float2(__uint_as_float(u << 16), __uint_as_float(u & 0xffff0000u));
}

// inclusive scan over blockDim = nw*64 threads (one value per thread)
__device__ inline int blk_scan_incl(int v, int* ws, int nw) {
  int t = threadIdx.x, lane = t & 63, w = t >> 6;
#pragma unroll
  for (int d = 1; d < 64; d <<= 1) {
    int u = __shfl_up(v, d, 64);
    if (lane >= d) v += u;
  }
  if (lane == 63) ws[w] = v;
  __syncthreads();
  if (w == 0) {
    int s = (lane < nw) ? ws[lane] : 0;
    for (int d = 1; d < nw; d <<= 1) {
      int u = __shfl_up(s, d, 64);
      if (lane >= d) s += u;
    }
    if (lane < nw) ws[lane] = s;
  }
  __syncthreads();
  if (w > 0) v += ws[w - 1];
  return v;
}

// ---- fused setup: GEMM1 (MFMA, W1 transposed in-block) + coarse hist + Wt2 prep + sentinels

__global__ __launch_bounds__(512) void k_setup(const int* __restrict__ dst, int E, int CH,
                                               int nb1, int* __restrict__ counts,
                                               const float* __restrict__ x,
                                               const float* __restrict__ W1,
                                               const float* __restrict__ Wmu,
                                               const float* __restrict__ Wls,
                                               ushort_t* __restrict__ Wt2,
                                               ushort_t* __restrict__ xWb,
                                               ushort_t* __restrict__ h,
                                               float* __restrict__ dinv, int N, int G1) {
  __shared__ ushort_t Ws[128][132];
  __shared__ uint_t cnt[NB1MAX];
  int b = blockIdx.x, t = threadIdx.x;
  if (b < G1) {
    // ---- GEMM1: xW = bf16(x) @ bf16(W1), bf16 out (unscaled). 128 rows, 8 waves. ----
#pragma unroll
    for (int it = 0; it < 16; it++) {
      int k = it * 8 + ((t >> 7) << 1);
      int j = t & 127;
      float a = W1[k * 128 + j];
      float bb = W1[(k + 1) * 128 + j];
      *(uint_t*)&Ws[j][k] = pack2bf(a, bb);
    }
    __syncthreads();
    int w = t >> 6, lane = t & 63;
    int rl = lane & 15, g = lane >> 4;
    int row = b * 128 + w * 16 + rl;
    bool valid = row < N;
    const float* Ar = x + (size_t)row * DIN + 4 * g;
    s4v af[8];
#pragma unroll
    for (int kk = 0; kk < 8; kk++) {
      float4 v = make_float4(0.f, 0.f, 0.f, 0.f);
      if (valid) v = *(const float4*)(Ar + kk * 16);
      s4v a;
      a[0] = (short)f2bf(v.x);
      a[1] = (short)f2bf(v.y);
      a[2] = (short)f2bf(v.z);
      a[3] = (short)f2bf(v.w);
      af[kk] = a;
    }
    f4v acc[8];
#pragma unroll
    for (int ct = 0; ct < 8; ct++) acc[ct] = (f4v)0.f;
#pragma unroll
    for (int kk = 0; kk < 8; kk++) {
      int ko = kk * 16 + 4 * g;
#pragma unroll
      for (int ct = 0; ct < 8; ct++) {
        s4v bb = *(s4v*)&Ws[ct * 16 + rl][ko];
        acc[ct] = MFMA16(af[kk], bb, acc[ct]);
      }
    }
    int gr0 = b * 128 + w * 16 + 4 * g;
#pragma unroll
    for (int i = 0; i < 4; i++) {
      int gr = gr0 + i;
      if (gr < N) {
#pragma unroll
        for (int ct = 0; ct < 8; ct++)
          xWb[(size_t)gr * HID + ct * 16 + rl] = f2bf(acc[ct][i]);
      }
    }
  } else if (b < G1 + NCHUNK) {
    // ---- coarse hist of dst>>BSH ----
    int c = b - G1;
    for (int i = t; i < nb1; i += 512) cnt[i] = 0;
    __syncthreads();
    int e0 = c * CH, e1 = min(E, e0 + CH);
    for (int i = e0 + t; i < e1; i += 512) atomicAdd(&cnt[((uint_t)dst[i]) >> BSH], 1u);
    __syncthreads();
    for (int i = t; i < nb1; i += 512) counts[c * nb1 + i] = (int)cnt[i];
  } else if (b < G1 + NCHUNK + 32) {
    // ---- Wt2 prep: bf16 col-major [j][k] of [Wmu | Wls] ----
    int idx = (b - G1 - NCHUNK) * 512 + t;  // 0..16383
    int j = idx >> 7, k = idx & 127;
    Wt2[j * 128 + k] = f2bf(j < 64 ? Wmu[k * 64 + j] : Wls[k * 64 + (j - 64)]);
  } else {
    // ---- sentinels ----
    if (t < 64) ((uint_t*)(xWb + (size_t)N * HID))[t] = 0;
    else if (t < 128) ((uint_t*)(h + (size_t)N * HID))[t - 64] = 0;
    else if (t == 128) dinv[N] = 0.f;
  }
}

// Phase B: per bucket, exclusive scan over NCHUNK chunks -> chunk_off; bucket totals.
__global__ __launch_bounds__(256) void k_bscan(const int* __restrict__ counts, int nb1,
                                               int* __restrict__ chunk_off,
                                               int* __restrict__ btot) {
  __shared__ int ws[8];
  __shared__ int shc;
  int b = blockIdx.x, t = threadIdx.x;
  int carry = 0;
#pragma unroll
  for (int r = 0; r < NCHUNK / 256 + 1; r++) {
    int idx = r * 256 + t;
    int v = (idx < NCHUNK) ? counts[idx * nb1 + b] : 0;
    int incl = blk_scan_incl(v, ws, 4) + carry;
    if (idx < NCHUNK) chunk_off[idx * nb1 + b] = incl - v;
    if (t == 255) shc = incl;
    __syncthreads();
    carry = shc;
  }
  if (t == 0) btot[b] = carry;
}

// Phase C: coarse scatter via in-block LDS counting sort -> coalesced global writes.
__global__ __launch_bounds__(256) void k_bscatter(const int* __restrict__ src,
                                                  const int* __restrict__ dst, int E, int CH,
                                                  int nb1, const int* __restrict__ btot,
                                                  const int* __restrict__ chunk_off,
                                                  uint_t* __restrict__ tmp) {
  __shared__ int ws[8];
  __shared__ uint_t cnt[NB1MAX];
  __shared__ uint_t lofs[NB1MAX];
  __shared__ uint_t gbase[NB1MAX];
  __shared__ uint_t ebuf[CHB * 256];
  __shared__ ushort_t bbuf[CHB * 256];
  int t = threadIdx.x, c = blockIdx.x;
  {
    int v = (t < nb1) ? btot[t] : 0;
    int incl = blk_scan_incl(v, ws, 4);
    if (t < nb1) {
      gbase[t] = (uint_t)(incl - v + chunk_off[c * nb1 + t]);
      cnt[t] = 0;
    }
  }
  __syncthreads();
  int e0 = c * CH, e1 = min(E, e0 + CH);
  int nloc = e1 - e0;
  uint_t pay[CHB];
  ushort_t bk[CHB], rk[CHB];
#pragma unroll
  for (int r = 0; r < CHB; r++) {
    int i = e0 + r * 256 + t;
    if (i < e1) {
      uint_t d = (uint_t)dst[i];
      uint_t s = (uint_t)src[i];
      uint_t b = d >> BSH;
      pay[r] = ((d & ((1u << BSH) - 1)) << 17) | s;
      bk[r] = (ushort_t)b;
      rk[r] = (ushort_t)atomicAdd(&cnt[b], 1u);
    }
  }
  __syncthreads();
  {  // exclusive scan of per-bucket counts -> lofs
    int v = (t < nb1) ? (int)cnt[t] : 0;
    int incl = blk_scan_incl(v, ws, 4);
    if (t < nb1) lofs[t] = (uint_t)(incl - v);
  }
  __syncthreads();
#pragma unroll
  for (int r = 0; r < CHB; r++) {
    int i = e0 + r * 256 + t;
    if (i < e1) {
      uint_t p = lofs[bk[r]] + rk[r];
      ebuf[p] = pay[r];
      bbuf[p] = bk[r];
    }
  }
  __syncthreads();
  for (int i = t; i < nloc; i += 256) {  // bucket-sorted -> piecewise-contiguous writes
    uint_t b = bbuf[i];
    tmp[gbase[b] + ((uint_t)i - lofs[b])] = ebuf[i];
  }
}

// Phase D: one 512-thread block per bucket. LDS hist + LDS-staged CSR window (pads
// prefilled with sentinel N), single coalesced write-out; emit row_ptr/row_end/dinv.
__global__ __launch_bounds__(512) void k_bfinal(const uint_t* __restrict__ tmp,
                                                const int* __restrict__ btot, int N, int nb1,
                                                uint_t* __restrict__ csr,
                                                int* __restrict__ row_ptr,
                                                int* __restrict__ row_end,
                                                float* __restrict__ dinv) {
  __shared__ int ws[8];
  __shared__ int sseg0, sseg1, sptot;
  __shared__ uint_t cnt[1 << BSH];
  __shared__ uint_t ppfx[1 << BSH];
  __shared__ uint_t cur[1 << BSH];
  __shared__ uint_t ebuf[EBMAX];
  int b = blockIdx.x, t = threadIdx.x;
  {
    int v = (t < nb1) ? btot[t] : 0;
    int incl = blk_scan_incl(v, ws, 8);
    if (t == b) {
      sseg0 = incl - v;
      sseg1 = incl;
    }
  }
  for (int i = t; i < (1 << BSH); i += 512) cnt[i] = 0;
  __syncthreads();
  int seg0 = sseg0, seg1 = sseg1;
  int pb = ((seg0 + 3) & ~3) + BSLACK * b;  // padded, 16B-aligned bucket base
  for (int i = seg0 + t; i < seg1; i += 512) atomicAdd(&cnt[tmp[i] >> 17], 1u);
  __syncthreads();
  if (t < 64) {  // wave 0: scan 512 padded counts, 8 per lane
    uint_t pc[8];
    uint_t s = 0;
#pragma unroll
    for (int k = 0; k < 8; k++) {
      pc[k] = (cnt[t * 8 + k] + 3u) & ~3u;
      s += pc[k];
    }
    int incl = (int)s;
#pragma unroll
    for (int d = 1; d < 64; d <<= 1) {
      int u = __shfl_up(incl, d, 64);
      if (t >= d) incl += u;
    }
    uint_t excl = (uint_t)incl - s;
#pragma unroll
    for (int k = 0; k < 8; k++) {
      ppfx[t * 8 + k] = excl;
      excl += pc[k];
    }
    if (t == 63) sptot = (int)excl;
  }
  __syncthreads();
  int ptot = sptot;
  int nd0 = b << BSH;
  for (int i = t; i < (1 << BSH); i += 512) {
    cur[i] = ppfx[i];
    int g = nd0 + i;
    if (g < N) {
      row_ptr[g] = pb + (int)ppfx[i];
      row_end[g] = pb + (int)(ppfx[i] + ((cnt[i] + 3u) & ~3u));
      dinv[g] = rsqrtf((float)cnt[i] + 1.0f);  // +1 = self-loop
    }
  }
  for (int i = t; i < ptot; i += 512) ebuf[i] = (uint_t)N;  // pad prefill
  __syncthreads();
  for (int i = seg0 + t; i < seg1; i += 512) {  // re-read tmp; scatter into LDS window
    uint_t v = tmp[i];
    uint_t pos = atomicAdd(&cur[v >> 17], 1u);
    ebuf[pos] = v & 0x1FFFFu;
  }
  __syncthreads();
  for (int i = t; i < ptot; i += 512) csr[pb + i] = ebuf[i];  // coalesced write-out
}

// ------ Layer-1 aggregation (one wave per node). xW unscaled -> gather dinv[src] per edge.
// out h' = dn * relu(dn*acc + bias), acc = dn*xW[node] + sum dinv[s]*xW[s].

__global__ __launch_bounds__(256) void k_agg1(const ushort_t* __restrict__ H,
                                              const int* __restrict__ row_ptr,
                                              const int* __restrict__ row_end,
                                              const uint_t* __restrict__ csr,
                                              const float* __restrict__ dinv,
                                              const float* __restrict__ bias,
                                              ushort_t* __restrict__ out, int n) {
  int node = (blockIdx.x * blockDim.x + threadIdx.x) >> 6;
  int lane = threadIdx.x & 63;
  if (node >= n) return;
  const char* Hb = (const char*)H;
  const char* Db = (const char*)dinv;
  uint_t loff = (uint_t)lane << 2;
  float dn = dinv[node];
  int j = row_ptr[node], end = row_end[node];
  float2 hs = bf2x2(*(const uint_t*)(Hb + ((size_t)(((uint_t)node << 8) | loff))));
  float ax = dn * hs.x, ay = dn * hs.y;  // self term (outer dn applied at end)
  if (j < end) {
    uint4 c = *(const uint4*)(csr + j);
    while (true) {
      int jn = j + 4;
      bool more = jn < end;
      uint4 cn;
      if (more) cn = *(const uint4*)(csr + jn);
      float w0 = *(const float*)(Db + (size_t)(c.x << 2));
      float w1 = *(const float*)(Db + (size_t)(c.y << 2));
      float w2 = *(const float*)(Db + (size_t)(c.z << 2));
      float w3 = *(const float*)(Db + (size_t)(c.w << 2));
      uint_t v0 = *(const uint_t*)(Hb + (size_t)((c.x << 8) | loff));
      uint_t v1 = *(const uint_t*)(Hb + (size_t)((c.y << 8) | loff));
      uint_t v2 = *(const uint_t*)(Hb + (size_t)((c.z << 8) | loff));
      uint_t v3 = *(const uint_t*)(Hb + (size_t)((c.w << 8) | loff));
      float2 f0 = bf2x2(v0), f1 = bf2x2(v1), f2 = bf2x2(v2), f3 = bf2x2(v3);
      ax += w0 * f0.x; ay += w0 * f0.y;
      ax += w1 * f1.x; ay += w1 * f1.y;
      ax += w2 * f2.x; ay += w2 * f2.y;
      ax += w3 * f3.x; ay += w3 * f3.y;
      if (!more) break;
      c = cn;
      j = jn;
    }
  }
  ax = fmaxf(dn * ax + bias[2 * lane], 0.f) * dn;  // prescale h' by dn for layer 2
  ay = fmaxf(dn * ay + bias[2 * lane + 1], 0.f) * dn;
  ((uint_t*)out)[(size_t)node * 64 + lane] = pack2bf(ax, ay);
}

// ------ Fused layer-2/3: wave owns 16 nodes SERIALLY (sum-of-degrees concentrates; no
// max-degree coupling). Aggregate h' rows -> per-wave LDS patch -> MFMA epilogue with
// B-frags from L1/L2-hot Wt2; write [mu|logstd] fp32 + bias directly.

__global__ __launch_bounds__(256) void k_agg2g(const ushort_t* __restrict__ H,
                                               const int* __restrict__ row_ptr,
                                               const int* __restrict__ row_end,
                                               const uint_t* __restrict__ csr,
                                               const float* __restrict__ dinv,
                                               const ushort_t* __restrict__ Wt2,
                                               const float* __restrict__ bmu,
                                               const float* __restrict__ bls,
                                               float* __restrict__ out, int n) {
  __shared__ ushort_t rows[4][16][132];  // per-wave staging (264B row stride)
  int t = threadIdx.x, w = t >> 6, lane = t & 63;
  int nbase = blockIdx.x * 64 + w * 16;
  const char* Hb = (const char*)H;
  uint_t loff = (uint_t)lane << 2;
  for (int r = 0; r < 16; r++) {  // ---- gather phase: 16 nodes sequentially ----
    int node = nbase + r;
    float ax = 0.f, ay = 0.f;
    if (node < n) {
      float dn = dinv[node];
      int j = row_ptr[node], end = row_end[node];
      float2 hs = bf2x2(*(const uint_t*)(Hb + ((size_t)(((uint_t)node << 8) | loff))));
      ax = hs.x;
      ay = hs.y;
      if (j < end) {
        uint4 c = *(const uint4*)(csr + j);
        while (true) {
          int jn = j + 4;
          bool more = jn < end;
          uint4 cn;
          if (more) cn = *(const uint4*)(csr + jn);
          uint_t v0 = *(const uint_t*)(Hb + (size_t)((c.x << 8) | loff));
          uint_t v1 = *(const uint_t*)(Hb + (size_t)((c.y << 8) | loff));
          uint_t v2 = *(const uint_t*)(Hb + (size_t)((c.z << 8) | loff));
          uint_t v3 = *(const uint_t*)(Hb + (size_t)((c.w << 8) | loff));
          float2 f0 = bf2x2(v0), f1 = bf2x2(v1), f2 = bf2x2(v2), f3 = bf2x2(v3);
          ax += f0.x + f1.x;
          ay += f0.y + f1.y;
          ax += f2.x + f3.x;
          ay += f2.y + f3.y;
          if (!more) break;
          c = cn;
          j = jn;
        }
      }
      ax *= dn;
      ay *= dn;
    }
    *(uint_t*)&rows[w][r][2 * lane] = pack2bf(ax, ay);
  }
  __syncthreads();  // mild coupling: max over 4 waves of sum-of-16-degrees (~+5%)
  // ---- MFMA epilogue: 16x128 @ 128x128 ----
  int rl = lane & 15, g = lane >> 4;
  s4v af[8];
#pragma unroll
  for (int kk = 0; kk < 8; kk++) af[kk] = *(s4v*)&rows[w][rl][kk * 16 + 4 * g];
#pragma unroll
  for (int ct = 0; ct < 8; ct++) {
    f4v acc = (f4v)0.f;
#pragma unroll
    for (int kk = 0; kk < 8; kk++) {
      s4v b = *(const s4v*)(Wt2 + (size_t)(ct * 16 + rl) * 128 + kk * 16 + 4 * g);
      acc = MFMA16(af[kk], b, acc);
    }
    int col = ct * 16 + rl;
    float bv;
    size_t obase;
    int cc;
    if (ct < 4) {
      bv = bmu[col];
      obase = 0;
      cc = col;
    } else {
      bv = bls[col - 64];
      obase = (size_t)n * DOUT;
      cc = col - 64;
    }
#pragma unroll
    for (int i = 0; i < 4; i++) {
      int nd = nbase + 4 * g + i;
      if (nd < n) out[obase + (size_t)nd * DOUT + cc] = acc[i] + bv;
    }
  }
}

// ---------------- launcher ----------------

extern "C" void kernel_launch(void* const* d_in, const int* in_sizes, int n_in,
                              void* d_out, int out_size, void* d_ws, size_t ws_size,
                              hipStream_t stream) {
  const float* x   = (const float*)d_in[0];
  const int*   ei  = (const int*)d_in[1];
  const float* W1  = (const float*)d_in[2];
  const float* b1  = (const float*)d_in[3];
  const float* Wmu = (const float*)d_in[4];
  const float* bmu = (const float*)d_in[5];
  const float* Wls = (const float*)d_in[6];
  const float* bls = (const float*)d_in[7];
  float* out = (float*)d_out;

  const int N = in_sizes[0] / DIN;
  const int E = in_sizes[1] / 2;
  const int* esrc = ei;
  const int* edst = ei + E;
  const int nb1 = ceil_div(N, 1 << BSH);  // <= 256
  const int CH = ceil_div(E, NCHUNK);     // <= CHB*256
  const int G1 = ceil_div(N, 128);

  char* ws = (char*)d_ws;
  size_t off = 0;
  auto alloc = [&](size_t bytes) -> void* {
    void* p = ws + off;
    off = (off + bytes + 255) & ~(size_t)255;
    return p;
  };
  ushort_t* xWb   = (ushort_t*)alloc((size_t)(N + 1) * HID * sizeof(ushort_t));  // gemm1 out
  ushort_t* h     = (ushort_t*)alloc((size_t)(N + 1) * HID * sizeof(ushort_t));  // h' (pre-scaled)
  uint_t* csr     = (uint_t*)alloc(((size_t)E + (size_t)(BSLACK + 8) * nb1 + 16) * 4);
  uint_t* tmp     = (uint_t*)alloc((size_t)E * 4);
  int* counts     = (int*)alloc((size_t)NCHUNK * nb1 * 4);
  int* chunk_off  = (int*)alloc((size_t)NCHUNK * nb1 * 4);
  int* btot       = (int*)alloc((size_t)nb1 * 4);
  int* row_ptr    = (int*)alloc((size_t)N * 4);
  int* row_end    = (int*)alloc((size_t)N * 4);
  float* dinv     = (float*)alloc((size_t)(N + 1) * 4);
  ushort_t* wt2b  = (ushort_t*)alloc((size_t)HID * HID * 2);
  (void)ws_size; (void)n_in; (void)out_size;

  // fused: gemm1 + coarse hist + Wt2 prep + sentinels
  k_setup<<<G1 + NCHUNK + 33, 512, 0, stream>>>(edst, E, CH, nb1, counts, x, W1, Wmu, Wls,
                                                wt2b, xWb, h, dinv, N, G1);
  k_bscan<<<nb1, 256, 0, stream>>>(counts, nb1, chunk_off, btot);
  k_bscatter<<<NCHUNK, 256, 0, stream>>>(esrc, edst, E, CH, nb1, btot, chunk_off, tmp);
  k_bfinal<<<nb1, 512, 0, stream>>>(tmp, btot, N, nb1, csr, row_ptr, row_end, dinv);

  // Layer 1: h' = dinv .* relu(Ahat @ xW + b1)   [dinv gathered per edge]
  k_agg1<<<ceil_div(N, 4), 256, 0, stream>>>(xWb, row_ptr, row_end, csr, dinv, b1, h, N);

  // Layer 2+3 fused (wave-serial 16 nodes): [mu|logstd] = (Ahat-sum h') @ Wt2 + b
  k_agg2g<<<ceil_div(N, 64), 256, 0, stream>>>(h, row_ptr, row_end, csr, dinv, wt2b, bmu, bls,
                                               out, N);
}

// Round 13
// 205.177 us; speedup vs baseline: 1.1351x; 1.1351x over previous
//
#include <hip/hip_runtime.h>

#define DIN 128
#define HID 128
#define DOUT 64
#define NCHUNK 784   // edge chunks (hist/scatter blocks); CH = ceil(E/784) must be <= 2048
#define CHB 8        // edges per thread in bscatter (CHB*256 >= CH)
#define BSH 9        // bucket covers 512 nodes; nb1 = ceil(N/512) must be <= 256
#define NB1MAX 256
#define BSLACK 1540  // per-bucket pad slack (multiple of 4, >= 3*512+4)
#define EBMAX 16384  // bfinal LDS staging entries (seg ~8.2K + pad ~1.5K << 16K)

typedef unsigned short ushort_t;
typedef unsigned int uint_t;
typedef __attribute__((ext_vector_type(4))) short s4v;
typedef __attribute__((ext_vector_type(4))) float f4v;

#if defined(__has_builtin)
#if __has_builtin(__builtin_amdgcn_mfma_f32_16x16x16bf16_1k)
#define MFMA16(a, b, c) __builtin_amdgcn_mfma_f32_16x16x16bf16_1k(a, b, c, 0, 0, 0)
#endif
#endif
#ifndef MFMA16
static __device__ inline f4v mfma16_asm(s4v a, s4v b, f4v c) {
  asm volatile("v_mfma_f32_16x16x16_bf16 %0, %1, %2, %0" : "+v"(c) : "v"(a), "v"(b));
  return c;
}
#define MFMA16(a, b, c) mfma16_asm(a, b, c)
#endif

static inline int ceil_div(int a, int b) { return (a + b - 1) / b; }

__device__ inline ushort_t f2bf(float f) {  // round-to-nearest-even
  uint_t u = __float_as_uint(f);
  u += 0x7fff + ((u >> 16) & 1);
  return (ushort_t)(u >> 16);
}
__device__ inline uint_t pack2bf(float a, float b) {
  return (uint_t)f2bf(a) | ((uint_t)f2bf(b) << 16);
}
__device__ inline float2 bf2x2(uint_t u) {  // unpack 2 bf16 -> 2 f32 (exact)
  return make_float2(__uint_as_float(u << 16), __uint_as_float(u & 0xffff0000u));
}

// inclusive scan over blockDim = nw*64 threads (one value per thread)
__device__ inline int blk_scan_incl(int v, int* ws, int nw) {
  int t = threadIdx.x, lane = t & 63, w = t >> 6;
#pragma unroll
  for (int d = 1; d < 64; d <<= 1) {
    int u = __shfl_up(v, d, 64);
    if (lane >= d) v += u;
  }
  if (lane == 63) ws[w] = v;
  __syncthreads();
  if (w == 0) {
    int s = (lane < nw) ? ws[lane] : 0;
    for (int d = 1; d < nw; d <<= 1) {
      int u = __shfl_up(s, d, 64);
      if (lane >= d) s += u;
    }
    if (lane < nw) ws[lane] = s;
  }
  __syncthreads();
  if (w > 0) v += ws[w - 1];
  return v;
}

// ---- fused setup: GEMM1 (MFMA, W1 transposed in-block) + coarse hist + Wt2 prep + sentinels

__global__ __launch_bounds__(512) void k_setup(const int* __restrict__ dst, int E, int CH,
                                               int nb1, int* __restrict__ counts,
                                               const float* __restrict__ x,
                                               const float* __restrict__ W1,
                                               const float* __restrict__ Wmu,
                                               const float* __restrict__ Wls,
                                               ushort_t* __restrict__ Wt2,
                                               ushort_t* __restrict__ xWb,
                                               ushort_t* __restrict__ h,
                                               float* __restrict__ dinv, int N, int G1) {
  __shared__ ushort_t Ws[128][132];
  __shared__ uint_t cnt[NB1MAX];
  int b = blockIdx.x, t = threadIdx.x;
  if (b < G1) {
    // ---- GEMM1: xW = bf16(x) @ bf16(W1), bf16 out (unscaled). 128 rows, 8 waves. ----
#pragma unroll
    for (int it = 0; it < 16; it++) {
      int k = it * 8 + ((t >> 7) << 1);
      int j = t & 127;
      float a = W1[k * 128 + j];
      float bb = W1[(k + 1) * 128 + j];
      *(uint_t*)&Ws[j][k] = pack2bf(a, bb);
    }
    __syncthreads();
    int w = t >> 6, lane = t & 63;
    int rl = lane & 15, g = lane >> 4;
    int row = b * 128 + w * 16 + rl;
    bool valid = row < N;
    const float* Ar = x + (size_t)row * DIN + 4 * g;
    s4v af[8];
#pragma unroll
    for (int kk = 0; kk < 8; kk++) {
      float4 v = make_float4(0.f, 0.f, 0.f, 0.f);
      if (valid) v = *(const float4*)(Ar + kk * 16);
      s4v a;
      a[0] = (short)f2bf(v.x);
      a[1] = (short)f2bf(v.y);
      a[2] = (short)f2bf(v.z);
      a[3] = (short)f2bf(v.w);
      af[kk] = a;
    }
    f4v acc[8];
#pragma unroll
    for (int ct = 0; ct < 8; ct++) acc[ct] = (f4v)0.f;
#pragma unroll
    for (int kk = 0; kk < 8; kk++) {
      int ko = kk * 16 + 4 * g;
#pragma unroll
      for (int ct = 0; ct < 8; ct++) {
        s4v bb = *(s4v*)&Ws[ct * 16 + rl][ko];
        acc[ct] = MFMA16(af[kk], bb, acc[ct]);
      }
    }
    int gr0 = b * 128 + w * 16 + 4 * g;
#pragma unroll
    for (int i = 0; i < 4; i++) {
      int gr = gr0 + i;
      if (gr < N) {
#pragma unroll
        for (int ct = 0; ct < 8; ct++)
          xWb[(size_t)gr * HID + ct * 16 + rl] = f2bf(acc[ct][i]);
      }
    }
  } else if (b < G1 + NCHUNK) {
    // ---- coarse hist of dst>>BSH ----
    int c = b - G1;
    for (int i = t; i < nb1; i += 512) cnt[i] = 0;
    __syncthreads();
    int e0 = c * CH, e1 = min(E, e0 + CH);
    for (int i = e0 + t; i < e1; i += 512) atomicAdd(&cnt[((uint_t)dst[i]) >> BSH], 1u);
    __syncthreads();
    for (int i = t; i < nb1; i += 512) counts[c * nb1 + i] = (int)cnt[i];
  } else if (b < G1 + NCHUNK + 32) {
    // ---- Wt2 prep: bf16 col-major [j][k] of [Wmu | Wls] ----
    int idx = (b - G1 - NCHUNK) * 512 + t;  // 0..16383
    int j = idx >> 7, k = idx & 127;
    Wt2[j * 128 + k] = f2bf(j < 64 ? Wmu[k * 64 + j] : Wls[k * 64 + (j - 64)]);
  } else {
    // ---- sentinels ----
    if (t < 64) ((uint_t*)(xWb + (size_t)N * HID))[t] = 0;
    else if (t < 128) ((uint_t*)(h + (size_t)N * HID))[t - 64] = 0;
    else if (t == 128) dinv[N] = 0.f;
  }
}

// Phase B: per bucket, exclusive scan over NCHUNK chunks -> chunk_off; bucket totals.
__global__ __launch_bounds__(256) void k_bscan(const int* __restrict__ counts, int nb1,
                                               int* __restrict__ chunk_off,
                                               int* __restrict__ btot) {
  __shared__ int ws[8];
  __shared__ int shc;
  int b = blockIdx.x, t = threadIdx.x;
  int carry = 0;
#pragma unroll
  for (int r = 0; r < NCHUNK / 256 + 1; r++) {
    int idx = r * 256 + t;
    int v = (idx < NCHUNK) ? counts[idx * nb1 + b] : 0;
    int incl = blk_scan_incl(v, ws, 4) + carry;
    if (idx < NCHUNK) chunk_off[idx * nb1 + b] = incl - v;
    if (t == 255) shc = incl;
    __syncthreads();
    carry = shc;
  }
  if (t == 0) btot[b] = carry;
}

// Phase C: coarse scatter via in-block LDS counting sort -> coalesced global writes.
__global__ __launch_bounds__(256) void k_bscatter(const int* __restrict__ src,
                                                  const int* __restrict__ dst, int E, int CH,
                                                  int nb1, const int* __restrict__ btot,
                                                  const int* __restrict__ chunk_off,
                                                  uint_t* __restrict__ tmp) {
  __shared__ int ws[8];
  __shared__ uint_t cnt[NB1MAX];
  __shared__ uint_t lofs[NB1MAX];
  __shared__ uint_t gbase[NB1MAX];
  __shared__ uint_t ebuf[CHB * 256];
  __shared__ ushort_t bbuf[CHB * 256];
  int t = threadIdx.x, c = blockIdx.x;
  {
    int v = (t < nb1) ? btot[t] : 0;
    int incl = blk_scan_incl(v, ws, 4);
    if (t < nb1) {
      gbase[t] = (uint_t)(incl - v + chunk_off[c * nb1 + t]);
      cnt[t] = 0;
    }
  }
  __syncthreads();
  int e0 = c * CH, e1 = min(E, e0 + CH);
  int nloc = e1 - e0;
  uint_t pay[CHB];
  ushort_t bk[CHB], rk[CHB];
#pragma unroll
  for (int r = 0; r < CHB; r++) {
    int i = e0 + r * 256 + t;
    if (i < e1) {
      uint_t d = (uint_t)dst[i];
      uint_t s = (uint_t)src[i];
      uint_t b = d >> BSH;
      pay[r] = ((d & ((1u << BSH) - 1)) << 17) | s;
      bk[r] = (ushort_t)b;
      rk[r] = (ushort_t)atomicAdd(&cnt[b], 1u);
    }
  }
  __syncthreads();
  {  // exclusive scan of per-bucket counts -> lofs
    int v = (t < nb1) ? (int)cnt[t] : 0;
    int incl = blk_scan_incl(v, ws, 4);
    if (t < nb1) lofs[t] = (uint_t)(incl - v);
  }
  __syncthreads();
#pragma unroll
  for (int r = 0; r < CHB; r++) {
    int i = e0 + r * 256 + t;
    if (i < e1) {
      uint_t p = lofs[bk[r]] + rk[r];
      ebuf[p] = pay[r];
      bbuf[p] = bk[r];
    }
  }
  __syncthreads();
  for (int i = t; i < nloc; i += 256) {  // bucket-sorted -> piecewise-contiguous writes
    uint_t b = bbuf[i];
    tmp[gbase[b] + ((uint_t)i - lofs[b])] = ebuf[i];
  }
}

// Phase D: one 512-thread block per bucket. LDS hist + LDS-staged CSR window (pads
// prefilled with sentinel N), single coalesced write-out; emit row_ptr/row_end/dinv.
__global__ __launch_bounds__(512) void k_bfinal(const uint_t* __restrict__ tmp,
                                                const int* __restrict__ btot, int N, int nb1,
                                                uint_t* __restrict__ csr,
                                                int* __restrict__ row_ptr,
                                                int* __restrict__ row_end,
                                                float* __restrict__ dinv) {
  __shared__ int ws[8];
  __shared__ int sseg0, sseg1, sptot;
  __shared__ uint_t cnt[1 << BSH];
  __shared__ uint_t ppfx[1 << BSH];
  __shared__ uint_t cur[1 << BSH];
  __shared__ uint_t ebuf[EBMAX];
  int b = blockIdx.x, t = threadIdx.x;
  {
    int v = (t < nb1) ? btot[t] : 0;
    int incl = blk_scan_incl(v, ws, 8);
    if (t == b) {
      sseg0 = incl - v;
      sseg1 = incl;
    }
  }
  for (int i = t; i < (1 << BSH); i += 512) cnt[i] = 0;
  __syncthreads();
  int seg0 = sseg0, seg1 = sseg1;
  int pb = ((seg0 + 3) & ~3) + BSLACK * b;  // padded, 16B-aligned bucket base
  for (int i = seg0 + t; i < seg1; i += 512) atomicAdd(&cnt[tmp[i] >> 17], 1u);
  __syncthreads();
  if (t < 64) {  // wave 0: scan 512 padded counts, 8 per lane
    uint_t pc[8];
    uint_t s = 0;
#pragma unroll
    for (int k = 0; k < 8; k++) {
      pc[k] = (cnt[t * 8 + k] + 3u) & ~3u;
      s += pc[k];
    }
    int incl = (int)s;
#pragma unroll
    for (int d = 1; d < 64; d <<= 1) {
      int u = __shfl_up(incl, d, 64);
      if (t >= d) incl += u;
    }
    uint_t excl = (uint_t)incl - s;
#pragma unroll
    for (int k = 0; k < 8; k++) {
      ppfx[t * 8 + k] = excl;
      excl += pc[k];
    }
    if (t == 63) sptot = (int)excl;
  }
  __syncthreads();
  int ptot = sptot;
  int nd0 = b << BSH;
  for (int i = t; i < (1 << BSH); i += 512) {
    cur[i] = ppfx[i];
    int g = nd0 + i;
    if (g < N) {
      row_ptr[g] = pb + (int)ppfx[i];
      row_end[g] = pb + (int)(ppfx[i] + ((cnt[i] + 3u) & ~3u));
      dinv[g] = rsqrtf((float)cnt[i] + 1.0f);  // +1 = self-loop
    }
  }
  for (int i = t; i < ptot; i += 512) ebuf[i] = (uint_t)N;  // pad prefill
  __syncthreads();
  for (int i = seg0 + t; i < seg1; i += 512) {  // re-read tmp; scatter into LDS window
    uint_t v = tmp[i];
    uint_t pos = atomicAdd(&cur[v >> 17], 1u);
    ebuf[pos] = v & 0x1FFFFu;
  }
  __syncthreads();
  for (int i = t; i < ptot; i += 512) csr[pb + i] = ebuf[i];  // coalesced write-out
}

// ------ Layer-1 aggregation (one wave per node). xW unscaled -> gather dinv[src] per edge.
// out h' = dn * relu(dn*acc + bias), acc = dn*xW[node] + sum dinv[s]*xW[s].

__global__ __launch_bounds__(256) void k_agg1(const ushort_t* __restrict__ H,
                                              const int* __restrict__ row_ptr,
                                              const int* __restrict__ row_end,
                                              const uint_t* __restrict__ csr,
                                              const float* __restrict__ dinv,
                                              const float* __restrict__ bias,
                                              ushort_t* __restrict__ out, int n) {
  int node = (blockIdx.x * blockDim.x + threadIdx.x) >> 6;
  int lane = threadIdx.x & 63;
  if (node >= n) return;
  const char* Hb = (const char*)H;
  const char* Db = (const char*)dinv;
  uint_t loff = (uint_t)lane << 2;
  float dn = dinv[node];
  int j = row_ptr[node], end = row_end[node];
  float2 hs = bf2x2(*(const uint_t*)(Hb + ((size_t)(((uint_t)node << 8) | loff))));
  float ax = dn * hs.x, ay = dn * hs.y;  // self term (outer dn applied at end)
  if (j < end) {
    uint4 c = *(const uint4*)(csr + j);
    while (true) {
      int jn = j + 4;
      bool more = jn < end;
      uint4 cn;
      if (more) cn = *(const uint4*)(csr + jn);
      float w0 = *(const float*)(Db + (size_t)(c.x << 2));
      float w1 = *(const float*)(Db + (size_t)(c.y << 2));
      float w2 = *(const float*)(Db + (size_t)(c.z << 2));
      float w3 = *(const float*)(Db + (size_t)(c.w << 2));
      uint_t v0 = *(const uint_t*)(Hb + (size_t)((c.x << 8) | loff));
      uint_t v1 = *(const uint_t*)(Hb + (size_t)((c.y << 8) | loff));
      uint_t v2 = *(const uint_t*)(Hb + (size_t)((c.z << 8) | loff));
      uint_t v3 = *(const uint_t*)(Hb + (size_t)((c.w << 8) | loff));
      float2 f0 = bf2x2(v0), f1 = bf2x2(v1), f2 = bf2x2(v2), f3 = bf2x2(v3);
      ax += w0 * f0.x; ay += w0 * f0.y;
      ax += w1 * f1.x; ay += w1 * f1.y;
      ax += w2 * f2.x; ay += w2 * f2.y;
      ax += w3 * f3.x; ay += w3 * f3.y;
      if (!more) break;
      c = cn;
      j = jn;
    }
  }
  ax = fmaxf(dn * ax + bias[2 * lane], 0.f) * dn;  // prescale h' by dn for layer 2
  ay = fmaxf(dn * ay + bias[2 * lane + 1], 0.f) * dn;
  ((uint_t*)out)[(size_t)node * 64 + lane] = pack2bf(ax, ay);
}

// ------ Layer-2 aggregation over pre-scaled h' (one wave per node): out = dn * sum, bf16.

__global__ __launch_bounds__(256) void k_agg2(const ushort_t* __restrict__ H,
                                              const int* __restrict__ row_ptr,
                                              const int* __restrict__ row_end,
                                              const uint_t* __restrict__ csr,
                                              const float* __restrict__ dinv,
                                              ushort_t* __restrict__ out, int n) {
  int node = (blockIdx.x * blockDim.x + threadIdx.x) >> 6;
  int lane = threadIdx.x & 63;
  if (node >= n) return;
  const char* Hb = (const char*)H;
  uint_t loff = (uint_t)lane << 2;
  float dn = dinv[node];
  int j = row_ptr[node], end = row_end[node];
  float2 hs = bf2x2(*(const uint_t*)(Hb + ((size_t)(((uint_t)node << 8) | loff))));
  float ax = hs.x, ay = hs.y;  // self term (h' already carries dinv factor)
  if (j < end) {
    uint4 c = *(const uint4*)(csr + j);
    while (true) {
      int jn = j + 4;
      bool more = jn < end;
      uint4 cn;
      if (more) cn = *(const uint4*)(csr + jn);
      uint_t v0 = *(const uint_t*)(Hb + (size_t)((c.x << 8) | loff));
      uint_t v1 = *(const uint_t*)(Hb + (size_t)((c.y << 8) | loff));
      uint_t v2 = *(const uint_t*)(Hb + (size_t)((c.z << 8) | loff));
      uint_t v3 = *(const uint_t*)(Hb + (size_t)((c.w << 8) | loff));
      float2 f0 = bf2x2(v0), f1 = bf2x2(v1), f2 = bf2x2(v2), f3 = bf2x2(v3);
      ax += f0.x + f1.x;
      ay += f0.y + f1.y;
      ax += f2.x + f3.x;
      ay += f2.y + f3.y;
      if (!more) break;
      c = cn;
      j = jn;
    }
  }
  ax *= dn;
  ay *= dn;
  ((uint_t*)out)[(size_t)node * 64 + lane] = pack2bf(ax, ay);
}

// ------- GEMM 2 (MFMA, fused): [mu | logstd] = agg2(bf16) @ Wt2 + b, fp32 out -------

__global__ __launch_bounds__(256) void k_gemm2(const ushort_t* __restrict__ A,
                                               const ushort_t* __restrict__ Wt,
                                               const float* __restrict__ bmu,
                                               const float* __restrict__ bls,
                                               float* __restrict__ out, int n) {
  __shared__ ushort_t Ws[128][132];
  int t = threadIdx.x;
#pragma unroll
  for (int i = 0; i < 16; i++) {
    int f = t + 256 * i;
    int rowj = f >> 5, seg = f & 31;
    *(uint2*)&Ws[rowj][seg * 4] = *(const uint2*)(Wt + rowj * 128 + seg * 4);
  }
  __syncthreads();
  int w = t >> 6, lane = t & 63;
  int rl = lane & 15, g = lane >> 4;
  int row = blockIdx.x * 64 + w * 16 + rl;
  bool valid = row < n;
  const ushort_t* Ar = A + (size_t)row * HID + 4 * g;
  s4v af[8];
#pragma unroll
  for (int kk = 0; kk < 8; kk++) {
    s4v a = (s4v)0;
    if (valid) a = *(const s4v*)(Ar + kk * 16);
    af[kk] = a;
  }
  f4v acc[8];
#pragma unroll
  for (int ct = 0; ct < 8; ct++) acc[ct] = (f4v)0.f;
#pragma unroll
  for (int kk = 0; kk < 8; kk++) {
    int ko = kk * 16 + 4 * g;
#pragma unroll
    for (int ct = 0; ct < 8; ct++) {
      s4v b = *(s4v*)&Ws[ct * 16 + rl][ko];
      acc[ct] = MFMA16(af[kk], b, acc[ct]);
    }
  }
  int gr0 = blockIdx.x * 64 + w * 16 + 4 * g;
#pragma unroll
  for (int ct = 0; ct < 8; ct++) {
    int col = ct * 16 + rl;
    float bv;
    size_t obase;
    int cc;
    if (ct < 4) {
      bv = bmu[col];
      obase = 0;
      cc = col;
    } else {
      bv = bls[col - 64];
      obase = (size_t)n * DOUT;
      cc = col - 64;
    }
#pragma unroll
    for (int i = 0; i < 4; i++) {
      int gr = gr0 + i;
      if (gr < n) out[obase + (size_t)gr * DOUT + cc] = acc[ct][i] + bv;
    }
  }
}

// ---------------- launcher ----------------

extern "C" void kernel_launch(void* const* d_in, const int* in_sizes, int n_in,
                              void* d_out, int out_size, void* d_ws, size_t ws_size,
                              hipStream_t stream) {
  const float* x   = (const float*)d_in[0];
  const int*   ei  = (const int*)d_in[1];
  const float* W1  = (const float*)d_in[2];
  const float* b1  = (const float*)d_in[3];
  const float* Wmu = (const float*)d_in[4];
  const float* bmu = (const float*)d_in[5];
  const float* Wls = (const float*)d_in[6];
  const float* bls = (const float*)d_in[7];
  float* out = (float*)d_out;

  const int N = in_sizes[0] / DIN;
  const int E = in_sizes[1] / 2;
  const int* esrc = ei;
  const int* edst = ei + E;
  const int nb1 = ceil_div(N, 1 << BSH);  // <= 256
  const int CH = ceil_div(E, NCHUNK);     // <= CHB*256
  const int G1 = ceil_div(N, 128);

  char* ws = (char*)d_ws;
  size_t off = 0;
  auto alloc = [&](size_t bytes) -> void* {
    void* p = ws + off;
    off = (off + bytes + 255) & ~(size_t)255;
    return p;
  };
  ushort_t* xWb   = (ushort_t*)alloc((size_t)(N + 1) * HID * sizeof(ushort_t));  // gemm1 out / agg2 out
  ushort_t* h     = (ushort_t*)alloc((size_t)(N + 1) * HID * sizeof(ushort_t));
  uint_t* csr     = (uint_t*)alloc(((size_t)E + (size_t)(BSLACK + 8) * nb1 + 16) * 4);
  uint_t* tmp     = (uint_t*)alloc((size_t)E * 4);
  int* counts     = (int*)alloc((size_t)NCHUNK * nb1 * 4);
  int* chunk_off  = (int*)alloc((size_t)NCHUNK * nb1 * 4);
  int* btot       = (int*)alloc((size_t)nb1 * 4);
  int* row_ptr    = (int*)alloc((size_t)N * 4);
  int* row_end    = (int*)alloc((size_t)N * 4);
  float* dinv     = (float*)alloc((size_t)(N + 1) * 4);
  ushort_t* wt2b  = (ushort_t*)alloc((size_t)HID * HID * 2);
  (void)ws_size; (void)n_in; (void)out_size;

  // fused: gemm1 + coarse hist + Wt2 prep + sentinels
  k_setup<<<G1 + NCHUNK + 33, 512, 0, stream>>>(edst, E, CH, nb1, counts, x, W1, Wmu, Wls,
                                                wt2b, xWb, h, dinv, N, G1);
  k_bscan<<<nb1, 256, 0, stream>>>(counts, nb1, chunk_off, btot);
  k_bscatter<<<NCHUNK, 256, 0, stream>>>(esrc, edst, E, CH, nb1, btot, chunk_off, tmp);
  k_bfinal<<<nb1, 512, 0, stream>>>(tmp, btot, N, nb1, csr, row_ptr, row_end, dinv);

  // Layer 1: h' = dinv .* relu(Ahat @ xW + b1)   [dinv gathered per edge]
  k_agg1<<<ceil_div(N, 4), 256, 0, stream>>>(xWb, row_ptr, row_end, csr, dinv, b1, h, N);

  // Layer 2+3: agg2 = Ahat-sum of h' (bf16), then [mu|logstd] = agg2 @ Wt2 + b
  k_agg2<<<ceil_div(N, 4), 256, 0, stream>>>(h, row_ptr, row_end, csr, dinv, xWb, N);
  k_gemm2<<<ceil_div(N, 64), 256, 0, stream>>>(xWb, wt2b, bmu, bls, out, N);
}